// Round 1
// baseline (993.002 us; speedup 1.0000x reference)
//
#include <hip/hip_runtime.h>
#include <cfloat>

// VQ quantizer: for each of N query rows (D=64 fp32), find nearest of K=512
// codebook rows (squared L2), output that codebook row.
//
// Structure: 1 query per lane. Codebook tiled into LDS (128 rows = 32 KiB per
// tile, 4 tiles). All lanes read the same LDS address per (k,d) -> broadcast,
// no bank conflicts. 4 independent FMA chains hide VALU latency.
// Top-2 tracking + fp64 refine for near-ties (gap <= 2e-3) so the argmin
// matches a high-precision reference even where fp32 rounding is ambiguous.

#define DDIM 64
#define KCB  512
#define TK   128          // codebook rows per LDS tile (32 KiB)
#define BLOCK 256
#define MARGIN 2e-3f

__device__ __forceinline__ double score64(const float* __restrict__ q,
                                          const float* __restrict__ crow) {
    // (||c||^2 - 2 q.c) in fp64; ||q||^2 is a per-query constant -> dropped
    double dot = 0.0, cn = 0.0;
    #pragma unroll
    for (int d = 0; d < DDIM; ++d) {
        double c = (double)crow[d];
        double x = (double)q[d];
        dot += x * c;
        cn  += c * c;
    }
    return cn - 2.0 * dot;
}

__global__ __launch_bounds__(BLOCK, 4) void vq_kernel(
    const float* __restrict__ ze, const float* __restrict__ cb,
    float* __restrict__ out, int nq)
{
    __shared__ float4 s_cb[TK][DDIM / 4];   // 32 KiB codebook tile
    __shared__ float  s_cn[KCB];            // 2 KiB ||c_k||^2

    const int tid = threadIdx.x;
    int q = blockIdx.x * BLOCK + tid;
    if (q >= nq) q = nq - 1;                // safe clamp (dup write of same data)

    // --- per-block codebook norms (fp32; only used for margin-level ranking)
    for (int k = tid; k < KCB; k += BLOCK) {
        const float4* row = (const float4*)(cb + (size_t)k * DDIM);
        float s0 = 0.f, s1 = 0.f, s2 = 0.f, s3 = 0.f;
        #pragma unroll
        for (int j = 0; j < DDIM / 4; ++j) {
            float4 v = row[j];
            s0 = fmaf(v.x, v.x, s0);
            s1 = fmaf(v.y, v.y, s1);
            s2 = fmaf(v.z, v.z, s2);
            s3 = fmaf(v.w, v.w, s3);
        }
        s_cn[k] = (s0 + s1) + (s2 + s3);
    }

    // --- load query into registers (64 VGPRs)
    float4 q4[DDIM / 4];
    {
        const float4* qrow = (const float4*)(ze + (size_t)q * DDIM);
        #pragma unroll
        for (int j = 0; j < DDIM / 4; ++j) q4[j] = qrow[j];
    }

    float best = FLT_MAX, second = FLT_MAX;
    int bestk = 0, secondk = 0;

    for (int t = 0; t < KCB; t += TK) {
        __syncthreads();   // also covers s_cn on first iteration
        // stage tile: TK*DDIM/4 = 2048 float4, 8 per thread, coalesced
        {
            const float4* src = (const float4*)(cb + (size_t)t * DDIM);
            float4* dst = (float4*)s_cb;
            #pragma unroll
            for (int j = 0; j < (TK * DDIM / 4) / BLOCK; ++j) {
                int idx = j * BLOCK + tid;
                dst[idx] = src[idx];
            }
        }
        __syncthreads();

        for (int kk = 0; kk < TK; ++kk) {
            float d0 = 0.f, d1 = 0.f, d2 = 0.f, d3 = 0.f;
            #pragma unroll
            for (int j = 0; j < DDIM / 4; ++j) {
                float4 c = s_cb[kk][j];        // wave-uniform addr -> broadcast
                d0 = fmaf(c.x, q4[j].x, d0);
                d1 = fmaf(c.y, q4[j].y, d1);
                d2 = fmaf(c.z, q4[j].z, d2);
                d3 = fmaf(c.w, q4[j].w, d3);
            }
            float dot  = (d0 + d1) + (d2 + d3);
            int   k    = t + kk;
            float dist = s_cn[k] - 2.f * dot;  // ||q||^2 const per query: dropped
            if (dist < best)        { second = best; secondk = bestk; best = dist; bestk = k; }
            else if (dist < second) { second = dist; secondk = k; }
        }
    }

    // --- fp64 refine for near-ties (rare: ~margin/mean_gap of queries)
    if (second - best <= MARGIN) {
        int a = min(bestk, secondk);
        int b = max(bestk, secondk);
        double da = score64((const float*)q4, cb + (size_t)a * DDIM);
        double db = score64((const float*)q4, cb + (size_t)b * DDIM);
        bestk = (db < da) ? b : a;             // strict <: first index wins ties
    }

    // --- gather selected codebook row to output
    {
        const float4* zrow = (const float4*)(cb + (size_t)bestk * DDIM);
        float4* orow = (float4*)(out + (size_t)q * DDIM);
        #pragma unroll
        for (int j = 0; j < DDIM / 4; ++j) orow[j] = zrow[j];
    }
}

extern "C" void kernel_launch(void* const* d_in, const int* in_sizes, int n_in,
                              void* d_out, int out_size, void* d_ws, size_t ws_size,
                              hipStream_t stream) {
    const float* ze = (const float*)d_in[0];
    const float* cb = (const float*)d_in[1];
    float* out = (float*)d_out;

    const int nq = in_sizes[0] / DDIM;                 // 524288
    const int grid = (nq + BLOCK - 1) / BLOCK;         // 2048
    vq_kernel<<<grid, BLOCK, 0, stream>>>(ze, cb, out, nq);
}

// Round 2
// 543.868 us; speedup vs baseline: 1.8258x; 1.8258x over previous
//
#include <hip/hip_runtime.h>
#include <cfloat>

// VQ quantizer via split-bf16 MFMA:
//   K_pre : convert codebook fp32 -> (hi,lo) bf16 in MFMA-fragment order (ws),
//           compute cn[k]=||c_k||^2 in fp64, zero the flag counter.
//   K1    : per wave: 32 queries x all 512 codes. dot ~= qh*ch + ql*ch + qh*cl
//           (3 MFMA products, 16x16x32 bf16). Track approx top-2 per query;
//           gap <= 1/128 -> append query to flag list. Write zq = cb[best].
//   K2    : fp64 exact full rescan for flagged queries (~0.1-0.5%), overwrite.

#define DDIM 64
#define KCB  512

typedef __attribute__((ext_vector_type(8))) short bf16x8;
typedef __attribute__((ext_vector_type(4))) float f32x4;

// ws byte layout
#define WS_CN    64                       // float cn[512]
#define WS_FRAG  4096                     // 128 KiB frag-ordered hi/lo bf16
#define WS_LIST  139264                   // int flagged-query list
#define DELTA    (1.0f/128.0f)

__device__ __forceinline__ short f2bf_rtne(float f) {
    unsigned int b = __float_as_uint(f);
    b += 0x7FFFu + ((b >> 16) & 1u);      // round-to-nearest-even
    return (short)(b >> 16);
}
__device__ __forceinline__ float bf2f(short s) {
    return __uint_as_float(((unsigned int)(unsigned short)s) << 16);
}

// ---------------- K_pre ----------------
__global__ void k_pre(const float* __restrict__ cb, char* __restrict__ ws) {
    int gid = blockIdx.x * 256 + threadIdx.x;          // 16*256 = 4096 threads
    if (gid == 0) *(int*)ws = 0;
    if (gid < KCB) {                                    // cn in fp64
        double s = 0.0;
        for (int d = 0; d < DDIM; ++d) {
            double c = (double)cb[gid * DDIM + d];
            s += c * c;
        }
        ((float*)(ws + WS_CN))[gid] = (float)s;
    }
    // one (hi,lo) chunk pair per thread: 4096 chunks of 8 bf16
    int t    = gid >> 10;          // tile of 128 codes
    int h    = gid & 1023;         // frag index within tile
    int lane = h & 63;
    int subkb = h >> 6;            // sub*2+kb
    int sub  = subkb >> 1;
    int kb   = subkb & 1;
    int code = t * 128 + sub * 16 + (lane & 15);
    int d0   = kb * 32 + ((lane >> 4) & 3) * 8;
    const float* src = cb + (size_t)code * DDIM + d0;
    union { short s[8]; float4 f4; } hi, lo;
    #pragma unroll
    for (int j = 0; j < 8; ++j) {
        float f = src[j];
        short hs = f2bf_rtne(f);
        hi.s[j] = hs;
        lo.s[j] = f2bf_rtne(f - bf2f(hs));
    }
    char* tb = ws + WS_FRAG + (size_t)t * 32768;
    *(float4*)(tb + (size_t)h * 16)         = hi.f4;
    *(float4*)(tb + 16384 + (size_t)h * 16) = lo.f4;
}

// ---------------- K1 ----------------
__global__ __launch_bounds__(256, 4) void k1(
    const float* __restrict__ ze, const float* __restrict__ cb,
    float* __restrict__ out, char* __restrict__ ws, int list_cap)
{
    __shared__ short s_b[16384];       // 32 KiB: hi [0,8192) lo [8192,16384) shorts
    __shared__ float s_cn[KCB];
    __shared__ int   s_bidx[128];

    const int tid  = threadIdx.x;
    const int wave = tid >> 6;
    const int lane = tid & 63;
    const int qb_block = blockIdx.x * 128;
    const int qb_wave  = qb_block + wave * 32;
    const int quad = (lane >> 4) & 3;

    for (int i = tid; i < KCB; i += 256) s_cn[i] = ((const float*)(ws + WS_CN))[i];

    // A fragments: 2 M-tiles x 2 k-blocks, hi+lo
    union { bf16x8 v; short s[8]; } qh[2][2], ql[2][2];
    #pragma unroll
    for (int m = 0; m < 2; ++m) {
        int row = qb_wave + m * 16 + (lane & 15);
        #pragma unroll
        for (int kb = 0; kb < 2; ++kb) {
            int d0 = kb * 32 + quad * 8;
            const float4* qs = (const float4*)(ze + (size_t)row * DDIM + d0);
            float4 a = qs[0], b = qs[1];
            float f[8] = {a.x,a.y,a.z,a.w,b.x,b.y,b.z,b.w};
            #pragma unroll
            for (int j = 0; j < 8; ++j) {
                short hs = f2bf_rtne(f[j]);
                qh[m][kb].s[j] = hs;
                ql[m][kb].s[j] = f2bf_rtne(f[j] - bf2f(hs));
            }
        }
    }

    float best[2][4], sec[2][4];
    int   bidx[2][4];
    #pragma unroll
    for (int m = 0; m < 2; ++m)
        #pragma unroll
        for (int r = 0; r < 4; ++r) { best[m][r] = FLT_MAX; sec[m][r] = FLT_MAX; bidx[m][r] = 0; }

    const bf16x8* s_hi = (const bf16x8*)s_b;          // 1024 frags
    const bf16x8* s_lo = s_hi + 1024;

    for (int t = 0; t < 4; ++t) {
        __syncthreads();
        {   // stage 32 KiB frag tile (contiguous, coalesced)
            const float4* src = (const float4*)(ws + WS_FRAG + (size_t)t * 32768);
            float4* dst = (float4*)s_b;
            #pragma unroll
            for (int j = 0; j < 8; ++j) dst[j * 256 + tid] = src[j * 256 + tid];
        }
        __syncthreads();

        for (int sub = 0; sub < 8; ++sub) {
            f32x4 acc0 = {0.f, 0.f, 0.f, 0.f};
            f32x4 acc1 = {0.f, 0.f, 0.f, 0.f};
            #pragma unroll
            for (int kb = 0; kb < 2; ++kb) {
                int fi = (sub * 2 + kb) * 64 + lane;
                bf16x8 bh = s_hi[fi];
                bf16x8 bl = s_lo[fi];
                acc0 = __builtin_amdgcn_mfma_f32_16x16x32_bf16(qh[0][kb].v, bh, acc0, 0, 0, 0);
                acc1 = __builtin_amdgcn_mfma_f32_16x16x32_bf16(qh[1][kb].v, bh, acc1, 0, 0, 0);
                acc0 = __builtin_amdgcn_mfma_f32_16x16x32_bf16(ql[0][kb].v, bh, acc0, 0, 0, 0);
                acc1 = __builtin_amdgcn_mfma_f32_16x16x32_bf16(ql[1][kb].v, bh, acc1, 0, 0, 0);
                acc0 = __builtin_amdgcn_mfma_f32_16x16x32_bf16(qh[0][kb].v, bl, acc0, 0, 0, 0);
                acc1 = __builtin_amdgcn_mfma_f32_16x16x32_bf16(qh[1][kb].v, bl, acc1, 0, 0, 0);
            }
            int code = t * 128 + sub * 16 + (lane & 15);
            float cnv = s_cn[code];
            #pragma unroll
            for (int r = 0; r < 4; ++r) {
                // m-tile 0
                float d0 = fmaf(acc0[r], -2.0f, cnv);
                float ns0 = fminf(sec[0][r], fmaxf(d0, best[0][r]));
                bidx[0][r] = (d0 < best[0][r]) ? code : bidx[0][r];
                best[0][r] = fminf(best[0][r], d0);
                sec[0][r]  = ns0;
                // m-tile 1
                float d1 = fmaf(acc1[r], -2.0f, cnv);
                float ns1 = fminf(sec[1][r], fmaxf(d1, best[1][r]));
                bidx[1][r] = (d1 < best[1][r]) ? code : bidx[1][r];
                best[1][r] = fminf(best[1][r], d1);
                sec[1][r]  = ns1;
            }
        }
    }

    // cross-lane top-2 merge over the 16 lanes of each quad-row group
    #pragma unroll
    for (int m = 0; m < 2; ++m) {
        #pragma unroll
        for (int r = 0; r < 4; ++r) {
            float b = best[m][r], s = sec[m][r];
            int   i = bidx[m][r];
            #pragma unroll
            for (int mask = 1; mask < 16; mask <<= 1) {
                float ob = __shfl_xor(b, mask);
                float os = __shfl_xor(s, mask);
                int   oi = __shfl_xor(i, mask);
                float ns = fminf(fmaxf(b, ob), fminf(s, os));
                i = (ob < b) ? oi : i;
                b = fminf(b, ob);
                s = ns;
            }
            if ((lane & 15) == 0) {
                int lrow = wave * 32 + m * 16 + quad * 4 + r;
                s_bidx[lrow] = i;
                if (s - b <= DELTA) {
                    int pos = atomicAdd((int*)ws, 1);
                    if (pos < list_cap)
                        ((int*)(ws + WS_LIST))[pos] = qb_block + lrow;
                }
            }
        }
    }

    __syncthreads();
    // block-wide zq gather: 128 rows x 64 floats
    {
        int row  = tid >> 1;
        int half = tid & 1;
        int bi = s_bidx[row];
        const float4* src = (const float4*)(cb + (size_t)bi * DDIM + half * 32);
        float4* dst = (float4*)(out + (size_t)(qb_block + row) * DDIM + half * 32);
        #pragma unroll
        for (int j = 0; j < 8; ++j) dst[j] = src[j];
    }
}

// ---------------- K2 ----------------
__global__ void k2(const float* __restrict__ ze, const float* __restrict__ cb,
                   float* __restrict__ out, char* __restrict__ ws, int list_cap)
{
    int nf = *(const int*)ws;
    if (nf > list_cap) nf = list_cap;
    const int* list = (const int*)(ws + WS_LIST);
    const int lane = threadIdx.x & 63;
    const int wgid = blockIdx.x * 4 + (threadIdx.x >> 6);   // 64 blocks * 4 waves

    for (int i = wgid; i < nf; i += 256) {
        int q = list[i];
        double dot[8];
        #pragma unroll
        for (int c = 0; c < 8; ++c) dot[c] = 0.0;
        for (int d = 0; d < DDIM; ++d) {
            double q2 = 2.0 * (double)ze[(size_t)q * DDIM + d];
            #pragma unroll
            for (int c = 0; c < 8; ++c) {
                double cd = (double)cb[(size_t)(lane * 8 + c) * DDIM + d];
                dot[c] = fma(cd, cd - q2, dot[c]);   // ||c||^2 - 2 q.c
            }
        }
        double v = dot[0]; int idx = lane * 8;
        #pragma unroll
        for (int c = 1; c < 8; ++c)
            if (dot[c] < v) { v = dot[c]; idx = lane * 8 + c; }
        for (int off = 1; off < 64; off <<= 1) {
            double ov = __shfl_xor(v, off);
            int    oi = __shfl_xor(idx, off);
            if (ov < v || (ov == v && oi < idx)) { v = ov; idx = oi; }
        }
        out[(size_t)q * DDIM + lane] = cb[(size_t)idx * DDIM + lane];
    }
}

extern "C" void kernel_launch(void* const* d_in, const int* in_sizes, int n_in,
                              void* d_out, int out_size, void* d_ws, size_t ws_size,
                              hipStream_t stream) {
    const float* ze = (const float*)d_in[0];
    const float* cb = (const float*)d_in[1];
    float* out = (float*)d_out;
    char* ws = (char*)d_ws;

    const int nq = in_sizes[0] / DDIM;                 // 524288
    int list_cap = 0;
    if (ws_size > WS_LIST + 4) list_cap = (int)((ws_size - WS_LIST) / 4);

    k_pre<<<16, 256, 0, stream>>>(cb, ws);
    k1<<<nq / 128, 256, 0, stream>>>(ze, cb, out, ws, list_cap);
    k2<<<64, 256, 0, stream>>>(ze, cb, out, ws, list_cap);
}

// Round 3
// 364.063 us; speedup vs baseline: 2.7276x; 1.4939x over previous
//
#include <hip/hip_runtime.h>
#include <cfloat>

// VQ quantizer via split-fp16 MFMA (3 products: qh*ch + ql'*ch + qh*cl', lo
// terms pre-scaled by 2048 to avoid fp16 subnormals, folded by 1/2048):
//   K_pre : codebook fp32 -> (hi, scaled-lo) f16 MFMA-fragment order in ws;
//           cn[k]=||c_k||^2 (fp64->fp32); zero flag counter.
//   K1    : wave = 32 queries x 512 codes. 4 independent MFMA chains.
//           approx top-2/query; gap <= 1e-3 -> flag list. zq = cb[best],
//           fully-coalesced gather writes.
//   K2    : fp64 exact rescan of flagged queries (expected O(100)):
//           one block/query slot, codebook in padded LDS, block argmin.

#define DDIM 64
#define KCB  512
#define DELTA 1e-3f
#define LO_SCALE 2048.0f
#define LO_INV   (1.0f/2048.0f)

typedef _Float16 f16x8 __attribute__((ext_vector_type(8)));
typedef float    f32x4 __attribute__((ext_vector_type(4)));

// ws layout (bytes)
#define WS_CN    64                        // float cn[512]
#define WS_FRAG  4096                      // 8 tiles * 16 KiB = 128 KiB
#define WS_LIST  (4096 + 131072)           // int flagged-query list

__device__ __forceinline__ void split16(float f, _Float16& hi, _Float16& lo) {
    hi = (_Float16)f;                      // RTNE
    float r = f - (float)hi;               // exact
    lo = (_Float16)(r * LO_SCALE);         // scaled: stays normal-range
}

// ---------------- K_pre ----------------
__global__ void k_pre(const float* __restrict__ cb, char* __restrict__ ws) {
    int gid = blockIdx.x * 256 + threadIdx.x;        // 16*256 = 4096
    if (gid == 0) *(int*)ws = 0;
    if (gid < KCB) {
        double s = 0.0;
        for (int d = 0; d < DDIM; ++d) {
            double c = (double)cb[gid * DDIM + d];
            s += c * c;
        }
        ((float*)(ws + WS_CN))[gid] = (float)s;
    }
    // one (hi,lo) frag pair per thread; tile = 64 codes, 8 tiles of 512 frags
    int t    = gid >> 9;
    int h    = gid & 511;
    int lane = h & 63;
    int subkb = h >> 6;                     // sub*2+kb, sub=0..3
    int sub  = subkb >> 1;
    int kb   = subkb & 1;
    int code = t * 64 + sub * 16 + (lane & 15);
    int d0   = kb * 32 + ((lane >> 4) & 3) * 8;
    const float* src = cb + (size_t)code * DDIM + d0;
    union { _Float16 h[8]; float4 f4; } hi, lo;
    #pragma unroll
    for (int j = 0; j < 8; ++j) split16(src[j], hi.h[j], lo.h[j]);
    char* tb = ws + WS_FRAG + (size_t)t * 16384;
    *(float4*)(tb + (size_t)h * 16)        = hi.f4;
    *(float4*)(tb + 8192 + (size_t)h * 16) = lo.f4;
}

// ---------------- K1 ----------------
__global__ __launch_bounds__(256, 4) void k1(
    const float* __restrict__ ze, const float* __restrict__ cb,
    float* __restrict__ out, char* __restrict__ ws, int list_cap)
{
    __shared__ f16x8 s_frag[1024];          // 16 KiB: hi [0,512) lo [512,1024)
    __shared__ float s_cn[KCB];             // 2 KiB
    __shared__ int   s_bidx[128];

    const int tid  = threadIdx.x;
    const int wave = tid >> 6;
    const int lane = tid & 63;
    const int quad = (lane >> 4) & 3;
    const int qb_block = blockIdx.x * 128;
    const int qb_wave  = qb_block + wave * 32;

    for (int i = tid; i < KCB; i += 256) s_cn[i] = ((const float*)(ws + WS_CN))[i];

    // A fragments: 2 M-tiles x 2 k-blocks, hi + scaled-lo
    union { f16x8 v; _Float16 h[8]; } qh[2][2], ql[2][2];
    #pragma unroll
    for (int m = 0; m < 2; ++m) {
        int row = qb_wave + m * 16 + (lane & 15);
        #pragma unroll
        for (int kb = 0; kb < 2; ++kb) {
            int d0 = kb * 32 + quad * 8;
            const float4* qs = (const float4*)(ze + (size_t)row * DDIM + d0);
            float4 a = qs[0], b = qs[1];
            float f[8] = {a.x,a.y,a.z,a.w,b.x,b.y,b.z,b.w};
            #pragma unroll
            for (int j = 0; j < 8; ++j) split16(f[j], qh[m][kb].h[j], ql[m][kb].h[j]);
        }
    }

    float best[2][4], sec[2][4];
    int   bidx[2][4];
    #pragma unroll
    for (int m = 0; m < 2; ++m)
        #pragma unroll
        for (int r = 0; r < 4; ++r) { best[m][r] = FLT_MAX; sec[m][r] = FLT_MAX; bidx[m][r] = 0; }

    for (int t = 0; t < 8; ++t) {
        __syncthreads();
        {   // stage 16 KiB tile, coalesced float4
            const float4* src = (const float4*)(ws + WS_FRAG + (size_t)t * 16384);
            float4* dst = (float4*)s_frag;
            #pragma unroll
            for (int j = 0; j < 4; ++j) dst[j * 256 + tid] = src[j * 256 + tid];
        }
        __syncthreads();

        #pragma unroll
        for (int sub = 0; sub < 4; ++sub) {
            // 4 independent accumulator chains (h/cross per m-tile)
            f32x4 ah0 = {0,0,0,0}, ah1 = {0,0,0,0};
            f32x4 as0 = {0,0,0,0}, as1 = {0,0,0,0};
            #pragma unroll
            for (int kb = 0; kb < 2; ++kb) {
                int fi = (sub * 2 + kb) * 64 + lane;
                f16x8 bh = s_frag[fi];
                f16x8 bl = s_frag[512 + fi];
                ah0 = __builtin_amdgcn_mfma_f32_16x16x32_f16(qh[0][kb].v, bh, ah0, 0, 0, 0);
                ah1 = __builtin_amdgcn_mfma_f32_16x16x32_f16(qh[1][kb].v, bh, ah1, 0, 0, 0);
                as0 = __builtin_amdgcn_mfma_f32_16x16x32_f16(ql[0][kb].v, bh, as0, 0, 0, 0);
                as1 = __builtin_amdgcn_mfma_f32_16x16x32_f16(ql[1][kb].v, bh, as1, 0, 0, 0);
                as0 = __builtin_amdgcn_mfma_f32_16x16x32_f16(qh[0][kb].v, bl, as0, 0, 0, 0);
                as1 = __builtin_amdgcn_mfma_f32_16x16x32_f16(qh[1][kb].v, bl, as1, 0, 0, 0);
            }
            int code = t * 64 + sub * 16 + (lane & 15);
            float cnv = s_cn[code];
            #pragma unroll
            for (int r = 0; r < 4; ++r) {
                float d0 = fmaf(as0[r], -2.0f * LO_INV, fmaf(ah0[r], -2.0f, cnv));
                float ns0 = fminf(sec[0][r], fmaxf(d0, best[0][r]));
                bidx[0][r] = (d0 < best[0][r]) ? code : bidx[0][r];
                best[0][r] = fminf(best[0][r], d0);
                sec[0][r]  = ns0;
                float d1 = fmaf(as1[r], -2.0f * LO_INV, fmaf(ah1[r], -2.0f, cnv));
                float ns1 = fminf(sec[1][r], fmaxf(d1, best[1][r]));
                bidx[1][r] = (d1 < best[1][r]) ? code : bidx[1][r];
                best[1][r] = fminf(best[1][r], d1);
                sec[1][r]  = ns1;
            }
        }
    }

    // cross-lane top-2 merge over 16 cols; ties -> smaller code index
    #pragma unroll
    for (int m = 0; m < 2; ++m) {
        #pragma unroll
        for (int r = 0; r < 4; ++r) {
            float b = best[m][r], s = sec[m][r];
            int   i = bidx[m][r];
            #pragma unroll
            for (int mask = 1; mask < 16; mask <<= 1) {
                float ob = __shfl_xor(b, mask);
                float os = __shfl_xor(s, mask);
                int   oi = __shfl_xor(i, mask);
                float ns = fminf(fmaxf(b, ob), fminf(s, os));
                i = (ob < b || (ob == b && oi < i)) ? oi : i;
                b = fminf(b, ob);
                s = ns;
            }
            if ((lane & 15) == 0) {
                int lrow = wave * 32 + m * 16 + quad * 4 + r;
                s_bidx[lrow] = i;
                if (s - b <= DELTA) {
                    int pos = atomicAdd((int*)ws, 1);
                    if (pos < list_cap)
                        ((int*)(ws + WS_LIST))[pos] = qb_block + lrow;
                }
            }
        }
    }

    __syncthreads();
    // coalesced gather: 4 threads/row, 2 passes -> full 64B lines/instr
    #pragma unroll
    for (int p = 0; p < 2; ++p) {
        int row = p * 64 + (tid >> 2);
        int qq  = tid & 3;
        int bi  = s_bidx[row];
        const float4* src = (const float4*)(cb + (size_t)bi * DDIM) + qq;
        float4* dst = (float4*)(out + (size_t)(qb_block + row) * DDIM) + qq;
        #pragma unroll
        for (int j = 0; j < 4; ++j) dst[j * 4] = src[j * 4];
    }
}

// ---------------- K2 ----------------
__global__ __launch_bounds__(256) void k2(
    const float* __restrict__ ze, const float* __restrict__ cb,
    float* __restrict__ out, char* __restrict__ ws, int list_cap)
{
    int nf = *(const int*)ws;
    if (nf > list_cap) nf = list_cap;
    if ((int)blockIdx.x >= nf) return;

    __shared__ float  s_cb[KCB * 65];       // padded rows: bank=(k+d)%32
    __shared__ float  s_q[DDIM];
    __shared__ double s_rv[256];
    __shared__ int    s_ri[256];

    const int tid = threadIdx.x;
    const int* list = (const int*)(ws + WS_LIST);

    // stage codebook into padded LDS (coalesced global reads)
    for (int idx = tid; idx < KCB * 16; idx += 256) {
        int row = idx >> 4, seg = idx & 15;
        float4 v = ((const float4*)(cb + (size_t)row * DDIM))[seg];
        float* d = s_cb + row * 65 + seg * 4;
        d[0] = v.x; d[1] = v.y; d[2] = v.z; d[3] = v.w;
    }

    for (int qi = blockIdx.x; qi < nf; qi += 256) {
        int q = list[qi];
        __syncthreads();
        if (tid < DDIM) s_q[tid] = ze[(size_t)q * DDIM + tid];
        __syncthreads();

        // thread handles codes tid and tid+256
        double da = 0.0, db = 0.0;
        for (int d = 0; d < DDIM; ++d) {
            double q2 = 2.0 * (double)s_q[d];
            double ca = (double)s_cb[tid * 65 + d];
            double cb2 = (double)s_cb[(tid + 256) * 65 + d];
            da = fma(ca, ca - q2, da);
            db = fma(cb2, cb2 - q2, db);
        }
        double v; int idx;
        if (db < da) { v = db; idx = tid + 256; } else { v = da; idx = tid; }
        s_rv[tid] = v; s_ri[tid] = idx;
        __syncthreads();
        for (int s = 128; s > 0; s >>= 1) {
            if (tid < s) {
                double ov = s_rv[tid + s]; int oi = s_ri[tid + s];
                if (ov < s_rv[tid] || (ov == s_rv[tid] && oi < s_ri[tid])) {
                    s_rv[tid] = ov; s_ri[tid] = oi;
                }
            }
            __syncthreads();
        }
        int bi = s_ri[0];
        if (tid < 16)
            ((float4*)(out + (size_t)q * DDIM))[tid] =
                ((const float4*)(cb + (size_t)bi * DDIM))[tid];
    }
}

extern "C" void kernel_launch(void* const* d_in, const int* in_sizes, int n_in,
                              void* d_out, int out_size, void* d_ws, size_t ws_size,
                              hipStream_t stream) {
    const float* ze = (const float*)d_in[0];
    const float* cb = (const float*)d_in[1];
    float* out = (float*)d_out;
    char* ws = (char*)d_ws;

    const int nq = in_sizes[0] / DDIM;                 // 524288
    int list_cap = 0;
    if (ws_size > WS_LIST + 4) list_cap = (int)((ws_size - WS_LIST) / 4);

    k_pre<<<16, 256, 0, stream>>>(cb, ws);
    k1<<<nq / 128, 256, 0, stream>>>(ze, cb, out, ws, list_cap);
    k2<<<256, 256, 0, stream>>>(ze, cb, out, ws, list_cap);
}